// Round 21
// baseline (39.503 us; speedup 1.0000x reference)
//
#include <hip/hip_runtime.h>

#define NB      32
#define NPB     16384
#define KTOP    2048
#define NF      64
#define NBINS   4096        // 12-bit bucket = key32 >> 20
#define NCH     8           // input chunks per batch (K1)
#define CROWS   2048        // rows per input chunk
#define CHSLOT  256         // candidate slots per sort chunk (8 chunks cover KTOP)
#define SCAP    1024        // sort buffer capacity
#define STHR    512

// Padded LDS index for the bitonic net (u64 elements).
__device__ __forceinline__ int PAD(int i) { return i + (i >> 5); }

// Monotone map: float -> uint32 such that float order == unsigned order.
__device__ __forceinline__ unsigned mono(float f) {
  unsigned u = __float_as_uint(f);
  return (u & 0x80000000u) ? ~u : (u | 0x80000000u);
}

// K1: 256 blocks x 1024 thr (one per 2048-row chunk): extract keys, build
// per-chunk hist (u16 subhist for K24's scan), then chunk-local counting
// sort by bin: h[] -> descending-bin start offsets, scatter u64 (key|~idx)
// into keybuf64[chunk] grouped by bin. For any batch threshold D, chunk c's
// candidates are exactly its first m_c entries.
__global__ __launch_bounds__(1024) void extract_hist_kernel(const float* __restrict__ in,
                                                            unsigned long long* __restrict__ keybuf64,
                                                            unsigned* __restrict__ subhist32) {
  __shared__ unsigned h[NBINS];                  // 16 KiB: hist -> start offsets
  __shared__ unsigned wtot[16], wsfx[16];
  const int g = blockIdx.x, tid = threadIdx.x;
  const int wid = tid >> 6, lane = tid & 63;
  for (int i = tid; i < NBINS; i += 1024) h[i] = 0;
  __syncthreads();
  const int row0 = g * CROWS;
  unsigned k0 = mono(in[(size_t)(row0 + tid) * NF]);
  unsigned k1 = mono(in[(size_t)(row0 + tid + 1024) * NF]);
  atomicAdd(&h[k0 >> 20], 1u);
  atomicAdd(&h[k1 >> 20], 1u);
  __syncthreads();

  // Write u16 subhist (reads h) + load my 4 bins for the scan (reads h).
  unsigned* out = subhist32 + (size_t)g * (NBINS / 2);
  for (int i = tid; i < NBINS / 2; i += 1024)
    out[i] = h[2 * i] | (h[2 * i + 1] << 16);    // counts <= 2048, fit u16
  unsigned c4[4]; unsigned s4 = 0;
#pragma unroll
  for (int j = 0; j < 4; ++j) { c4[j] = h[4 * tid + j]; s4 += c4[j]; }
  unsigned p = s4;                               // inclusive suffix over lanes
  for (int off = 1; off < 64; off <<= 1) {
    unsigned t = __shfl_down(p, off);
    if (lane + off < 64) p += t;
  }
  if (lane == 0) wtot[wid] = p;
  __syncthreads();                               // all h reads done; wtot ready
  if (wid == 0 && lane < 16) {
    unsigned own = wtot[lane];
    unsigned p2 = own;
    for (int off = 1; off < 16; off <<= 1) {
      unsigned t = __shfl_down(p2, off);
      if (lane + off < 16) p2 += t;
    }
    wsfx[lane] = p2 - own;                       // totals of waves above
  }
  __syncthreads();
  unsigned run = wsfx[wid] + (p - s4);           // keys in bins > my top bin
#pragma unroll
  for (int j = 3; j >= 0; --j) {                 // h[bin] := start offset
    unsigned ofs = run; run += c4[j];
    h[4 * tid + j] = ofs;
  }
  __syncthreads();

  // Scatter: bin-grouped u64 (key<<32 | ~batch_local_idx) into chunk region.
  {
    unsigned l0 = (unsigned)((row0 + tid) & (NPB - 1));
    unsigned l1 = (unsigned)((row0 + tid + 1024) & (NPB - 1));
    unsigned s0 = atomicAdd(&h[k0 >> 20], 1u);
    unsigned s1 = atomicAdd(&h[k1 >> 20], 1u);
    unsigned long long* kb = keybuf64 + (size_t)g * CROWS;
    kb[s0] = ((unsigned long long)k0 << 32) | (unsigned)~l0;
    kb[s1] = ((unsigned long long)k1 << 32) | (unsigned)~l1;
  }
}

// K24: 256 blocks (8 per batch; block (b,q) owns slots [E(256q), E(256q+256))).
// Preamble: batch scan from sub-hists -> D/N/ab/E1/E2 (unchanged); per-chunk
// candidate counts m_c from a subhist reload; pull reads ONLY the ~2300 true
// candidates (chunk-region prefixes), places via consistent per-bin LDS
// counters; wave-cooperative sort; gather. (R20 champion otherwise.)
__global__ __launch_bounds__(STHR) void select_sort_gather_kernel(const float* __restrict__ in,
                                                                  const unsigned long long* __restrict__ keybuf64,
                                                                  const unsigned short* __restrict__ subhist,
                                                                  float* __restrict__ out) {
  __shared__ unsigned ab_lds[NBINS];             // 16 KiB: slot counters (raw ab)
  __shared__ unsigned long long sb[SCAP + (SCAP >> 5)];   // 8.25 KiB padded
  __shared__ unsigned wtot[8], wsfx[8];
  __shared__ unsigned shE[2];
  __shared__ unsigned sh_D, sh_N;
  __shared__ unsigned sh_mc[NCH], mpre[NCH + 1];

  const int g = blockIdx.x, tid = threadIdx.x;
  const int b = g >> 3, q = g & 7;
  const int wid = tid >> 6, lane = tid & 63;
  const unsigned x1 = (unsigned)q * CHSLOT, x2 = x1 + CHSLOT;

  if (tid < 2) shE[tid] = 0xffffffffu;
  if (tid >= 2 && tid < 2 + NCH) sh_mc[tid - 2] = 0;

  // ---- Batch scan: totals for my 8 bins [8*tid, 8*tid+8). ----
  unsigned tot[8];
#pragma unroll
  for (int j = 0; j < 8; ++j) tot[j] = 0;
#pragma unroll
  for (int c = 0; c < NCH; ++c) {
    const uint4 v = *(const uint4*)(subhist + (size_t)(b * NCH + c) * NBINS + 8 * tid);
    tot[0] += v.x & 0xffffu; tot[1] += v.x >> 16;
    tot[2] += v.y & 0xffffu; tot[3] += v.y >> 16;
    tot[4] += v.z & 0xffffu; tot[5] += v.z >> 16;
    tot[6] += v.w & 0xffffu; tot[7] += v.w >> 16;
  }
  unsigned s = 0;
#pragma unroll
  for (int j = 0; j < 8; ++j) s += tot[j];

  unsigned p = s;                                // inclusive suffix over lanes
  for (int off = 1; off < 64; off <<= 1) {
    unsigned t = __shfl_down(p, off);
    if (lane + off < 64) p += t;
  }
  if (lane == 0) wtot[wid] = p;
  __syncthreads();
  if (wid == 0) {
    unsigned own = (lane < 8) ? wtot[lane] : 0;
    unsigned p2 = own;
    for (int off = 1; off < 8; off <<= 1) {
      unsigned t = __shfl_down(p2, off);
      if (lane + off < 8) p2 += t;
    }
    if (lane < 8) wsfx[lane] = p2 - own;         // totals of waves above
  }
  __syncthreads();

  unsigned run = wsfx[wid] + (p - s);            // keys strictly above my bins
  unsigned ab[8];
#pragma unroll
  for (int j = 7; j >= 0; --j) {
    ab[j] = run;                                 // above[bin 8*tid+j]
    run += tot[j];
    if (ab[j] < KTOP && run >= KTOP) {           // exactly one bin satisfies
      sh_D = (unsigned)(8 * tid + j);
      sh_N = run;                                // total candidate count
    }
  }

  // ---- Chunk boundaries: E1 = min ab >= x1, E2 = min ab >= x2. ----
  unsigned m1 = 0xffffffffu, m2 = 0xffffffffu;
#pragma unroll
  for (int j = 0; j < 8; ++j) {
    if (ab[j] >= x1 && ab[j] < m1) m1 = ab[j];
    if (ab[j] >= x2 && ab[j] < m2) m2 = ab[j];
  }
  for (int off = 1; off < 64; off <<= 1) {
    unsigned t1 = __shfl_xor(m1, off), t2 = __shfl_xor(m2, off);
    m1 = m1 < t1 ? m1 : t1;
    m2 = m2 < t2 ? m2 : t2;
  }
  if (lane == 0) { atomicMin(&shE[0], m1); atomicMin(&shE[1], m2); }
  __syncthreads();

  const unsigned D = sh_D, N = sh_N;
  const unsigned E1 = shE[0];
  unsigned E2 = (x2 >= N) ? N : shE[1];
  if (E2 > N) E2 = N;
  if (E1 >= KTOP || E1 >= N) return;             // uniform exit: no output here
  unsigned len = E2 - E1;
  if (len == 0) return;
  if (len > SCAP) len = SCAP;                    // safety (degenerate data only)

  // ---- Seed slot counters (raw ab); zero sb tail; per-chunk m_c. ----
#pragma unroll
  for (int j = 0; j < 8; ++j) ab_lds[8 * tid + j] = ab[j];
  unsigned S = 256;
  while (S < len) S <<= 1;                       // sort size, <= SCAP
  for (unsigned e = len + tid; e < S; e += STHR) sb[PAD(e)] = 0;
  if (8 * tid + 7 >= (int)D) {                   // m_c = sum_{bin>=D} cnt[c][bin]
#pragma unroll
    for (int c = 0; c < NCH; ++c) {
      const uint4 v = *(const uint4*)(subhist + (size_t)(b * NCH + c) * NBINS + 8 * tid);
      unsigned cc[8] = {v.x & 0xffffu, v.x >> 16, v.y & 0xffffu, v.y >> 16,
                        v.z & 0xffffu, v.z >> 16, v.w & 0xffffu, v.w >> 16};
      unsigned m = 0;
#pragma unroll
      for (int j = 0; j < 8; ++j) if ((unsigned)(8 * tid + j) >= D) m += cc[j];
      if (m) atomicAdd(&sh_mc[c], m);
    }
  }
  __syncthreads();
  if (tid == 0) {
    unsigned acc = 0;
    for (int c = 0; c < NCH; ++c) { mpre[c] = acc; acc += sh_mc[c]; }
    mpre[NCH] = acc;
  }
  __syncthreads();

  // ---- Pull: read ONLY the candidates (chunk-region prefixes), flattened. ----
  unsigned mp[NCH + 1];
#pragma unroll
  for (int c = 0; c <= NCH; ++c) mp[c] = mpre[c];
  const unsigned M = mp[NCH];
  const unsigned long long* kb = keybuf64 + (size_t)b * NPB;
  for (unsigned u = tid; u < M; u += STHR) {
    int c = 0;
#pragma unroll
    for (int cc = 1; cc < NCH; ++cc) c += (u >= mp[cc]);
    unsigned long long kv = kb[(size_t)c * CROWS + (u - mp[c])];
    unsigned bin = (unsigned)(kv >> 52);
    unsigned slot = atomicAdd(&ab_lds[bin], 1u);
    if (slot - E1 < len) sb[PAD(slot - E1)] = kv; // mine: slot in [E1, E2)
  }
  __syncthreads();

  // ---- Wave-cooperative bitonic sort, descending, adaptive size S. ----
  const int nseg = (int)(S >> 7);                // 128-elem segments (2/4/8)
  const int g0 = 128 * wid + lane;
  const int g1 = g0 + 64;
  unsigned long long r0 = 0, r1 = 0;

  if (wid < nseg) {                              // Phase A: 128-sort in regs
    r0 = sb[PAD(g0)]; r1 = sb[PAD(g1)];
    for (unsigned size = 2; size <= 128; size <<= 1) {
      const bool d0 = ((g0 & size) == 0), d1 = ((g1 & size) == 0);
      for (unsigned st = size >> 1; st >= 1; st >>= 1) {
        if (st == 64) {
          if ((r0 < r1) == d0) { unsigned long long t_ = r0; r0 = r1; r1 = t_; }
        } else {
          unsigned long long y0 = __shfl_xor(r0, (int)st);
          unsigned long long y1 = __shfl_xor(r1, (int)st);
          const bool lower = ((lane & st) == 0);
          r0 = ((d0 == lower) == (r0 > y0)) ? r0 : y0;
          r1 = ((d1 == lower) == (r1 > y1)) ? r1 : y1;
        }
      }
    }
    sb[PAD(g0)] = r0; sb[PAD(g1)] = r1;
  }
  __syncthreads();

  for (unsigned size = 256; size <= S; size <<= 1) {   // Phase B: merges
    for (unsigned st = size >> 1; st >= 128; st >>= 1) {
      if (tid < (int)(S / 2)) {
        int pos = 2 * tid - (tid & ((int)st - 1));
        bool desc = ((pos & size) == 0);
        unsigned long long a = sb[PAD(pos)], bb = sb[PAD(pos + (int)st)];
        if (desc ? (a < bb) : (a > bb)) { sb[PAD(pos)] = bb; sb[PAD(pos + (int)st)] = a; }
      }
      __syncthreads();
    }
    if (wid < nseg) {                            // final 128-merge in regs
      r0 = sb[PAD(g0)]; r1 = sb[PAD(g1)];
      const bool d = (((unsigned)(128 * wid) & size) == 0);
      if ((r0 < r1) == d) { unsigned long long t_ = r0; r0 = r1; r1 = t_; }
      for (unsigned st = 32; st >= 1; st >>= 1) {
        unsigned long long y0 = __shfl_xor(r0, (int)st);
        unsigned long long y1 = __shfl_xor(r1, (int)st);
        const bool lower = ((lane & st) == 0);
        r0 = ((d == lower) == (r0 > y0)) ? r0 : y0;
        r1 = ((d == lower) == (r1 > y1)) ? r1 : y1;
      }
      sb[PAD(g0)] = r0; sb[PAD(g1)] = r1;
    }
    __syncthreads();
  }

  // ---- Gather output rows [E1, gend). ----
  const unsigned gend = (E2 < KTOP) ? E2 : KTOP;
  const int glen = (int)(gend - E1);
  const float4* inb = (const float4*)(in + (size_t)b * NPB * NF);
  float4* outb = (float4*)(out + ((size_t)b * KTOP + E1) * NF);
  for (int u = tid; u < glen * 16; u += STHR) {
    int r = u >> 4, f4 = u & 15;
    unsigned long long kv = sb[PAD(r)];
    int gi = (int)(~(unsigned)(kv & 0xffffffffu));
    outb[(size_t)r * 16 + f4] = inb[(size_t)gi * 16 + f4];
  }
}

extern "C" void kernel_launch(void* const* d_in, const int* in_sizes, int n_in,
                              void* d_out, int out_size, void* d_ws, size_t ws_size,
                              hipStream_t stream) {
  const float* in = (const float*)d_in[0];
  float* out = (float*)d_out;

  // d_ws layout: keybuf64 @0 (4 MiB, bin-grouped u64), subhist u16 @4 MiB (2 MiB).
  unsigned long long* keybuf64 = (unsigned long long*)d_ws;
  unsigned* subhist32 = (unsigned*)((char*)d_ws + (4u << 20));
  unsigned short* subhist16 = (unsigned short*)subhist32;

  extract_hist_kernel<<<NB * NCH, 1024, 0, stream>>>(in, keybuf64, subhist32);
  select_sort_gather_kernel<<<NB * NCH, STHR, 0, stream>>>(in, keybuf64, subhist16, out);
}

// Round 22
// 38.432 us; speedup vs baseline: 1.0279x; 1.0279x over previous
//
#include <hip/hip_runtime.h>

#define NB      32
#define NPB     16384
#define KTOP    2048
#define NF      64
#define NBINS   4096        // 12-bit bucket = key32 >> 20
#define NCH     8           // input chunks per batch (K1)
#define CROWS   2048        // rows per input chunk
#define CHSLOT  256         // candidate slots per sort chunk (8 chunks cover KTOP)
#define SCAP    1024        // sort buffer capacity
#define STHR    512

// Padded LDS index for the bitonic net (u64 elements).
__device__ __forceinline__ int PAD(int i) { return i + (i >> 5); }

// Monotone map: float -> uint32 such that float order == unsigned order.
__device__ __forceinline__ unsigned mono(float f) {
  unsigned u = __float_as_uint(f);
  return (u & 0x80000000u) ? ~u : (u | 0x80000000u);
}

// K1: 256 blocks x 1024 thr (one block per 2048-row chunk): extract key
// column + private per-chunk u16 histogram (packed u32 stores).
// Cost is sector-granularity bound: 1 x 64B sector per 256B row (~134 MB L3).
__global__ __launch_bounds__(1024) void extract_hist_kernel(const float* __restrict__ in,
                                                            unsigned* __restrict__ keybuf,
                                                            unsigned* __restrict__ subhist32) {
  __shared__ unsigned h[NBINS];                  // 16 KiB
  const int g = blockIdx.x, tid = threadIdx.x;
  for (int i = tid; i < NBINS; i += 1024) h[i] = 0;
  __syncthreads();
  const int row0 = g * CROWS;
  unsigned k0 = mono(in[(size_t)(row0 + tid) * NF]);
  unsigned k1 = mono(in[(size_t)(row0 + tid + 1024) * NF]);
  keybuf[row0 + tid] = k0;
  keybuf[row0 + tid + 1024] = k1;
  atomicAdd(&h[k0 >> 20], 1u);
  atomicAdd(&h[k1 >> 20], 1u);
  __syncthreads();
  unsigned* out = subhist32 + (size_t)g * (NBINS / 2);
  for (int i = tid; i < NBINS / 2; i += 1024)
    out[i] = h[2 * i] | (h[2 * i + 1] << 16);    // counts <= 2048, fit u16
}

// K24: R13 structure; wave-cooperative bitonic sort (R20): each wave sorts
// a 128-elem segment in registers (shfl_xor, 0 barriers), cross-segment
// strides (>=128) via LDS, final 128-merges in registers. 55 -> 10 barriers.
__global__ __launch_bounds__(STHR) void select_sort_gather_kernel(const float* __restrict__ in,
                                                                  const unsigned* __restrict__ keybuf,
                                                                  const unsigned short* __restrict__ subhist,
                                                                  float* __restrict__ out) {
  __shared__ unsigned ab_lds[NBINS];             // 16 KiB: slot counters
  __shared__ unsigned long long sb[SCAP + (SCAP >> 5)];   // 8.25 KiB padded
  __shared__ unsigned wtot[8], wsfx[8];
  __shared__ unsigned shE[2];
  __shared__ unsigned sh_D, sh_N;

  const int g = blockIdx.x, tid = threadIdx.x;
  const int b = g >> 3, q = g & 7;
  const int wid = tid >> 6, lane = tid & 63;
  const unsigned x1 = (unsigned)q * CHSLOT, x2 = x1 + CHSLOT;

  if (tid < 2) shE[tid] = 0xffffffffu;

  // ---- Batch scan: totals for my 8 bins [8*tid, 8*tid+8). ----
  unsigned tot[8];
#pragma unroll
  for (int j = 0; j < 8; ++j) tot[j] = 0;
#pragma unroll
  for (int c = 0; c < NCH; ++c) {
    const uint4 v = *(const uint4*)(subhist + (size_t)(b * NCH + c) * NBINS + 8 * tid);
    tot[0] += v.x & 0xffffu; tot[1] += v.x >> 16;
    tot[2] += v.y & 0xffffu; tot[3] += v.y >> 16;
    tot[4] += v.z & 0xffffu; tot[5] += v.z >> 16;
    tot[6] += v.w & 0xffffu; tot[7] += v.w >> 16;
  }
  unsigned s = 0;
#pragma unroll
  for (int j = 0; j < 8; ++j) s += tot[j];

  unsigned p = s;                                // inclusive suffix over lanes
  for (int off = 1; off < 64; off <<= 1) {
    unsigned t = __shfl_down(p, off);
    if (lane + off < 64) p += t;
  }
  if (lane == 0) wtot[wid] = p;
  __syncthreads();
  if (wid == 0) {
    unsigned own = (lane < 8) ? wtot[lane] : 0;
    unsigned p2 = own;
    for (int off = 1; off < 8; off <<= 1) {
      unsigned t = __shfl_down(p2, off);
      if (lane + off < 8) p2 += t;
    }
    if (lane < 8) wsfx[lane] = p2 - own;         // totals of waves above
  }
  __syncthreads();

  unsigned run = wsfx[wid] + (p - s);            // keys strictly above my bins
  unsigned ab[8];
#pragma unroll
  for (int j = 7; j >= 0; --j) {
    ab[j] = run;                                 // above[bin 8*tid+j]
    run += tot[j];
    if (ab[j] < KTOP && run >= KTOP) {           // exactly one bin satisfies
      sh_D = (unsigned)(8 * tid + j);
      sh_N = run;                                // total candidate count
    }
  }

  // ---- Chunk boundaries: E1 = min ab >= x1, E2 = min ab >= x2. ----
  unsigned m1 = 0xffffffffu, m2 = 0xffffffffu;
#pragma unroll
  for (int j = 0; j < 8; ++j) {
    if (ab[j] >= x1 && ab[j] < m1) m1 = ab[j];
    if (ab[j] >= x2 && ab[j] < m2) m2 = ab[j];
  }
  for (int off = 1; off < 64; off <<= 1) {
    unsigned t1 = __shfl_xor(m1, off), t2 = __shfl_xor(m2, off);
    m1 = m1 < t1 ? m1 : t1;
    m2 = m2 < t2 ? m2 : t2;
  }
  if (lane == 0) { atomicMin(&shE[0], m1); atomicMin(&shE[1], m2); }
  __syncthreads();

  const unsigned D = sh_D, N = sh_N;
  const unsigned E1 = shE[0];
  unsigned E2 = (x2 >= N) ? N : shE[1];
  if (E2 > N) E2 = N;
  if (E1 >= KTOP || E1 >= N) return;             // uniform exit: no output here
  unsigned len = E2 - E1;
  if (len == 0) return;
  if (len > SCAP) len = SCAP;                    // safety (degenerate data only)

  // ---- Seed slot counters (ab - E1; foreign bins wrap/overflow -> reject). ----
#pragma unroll
  for (int j = 0; j < 8; ++j) ab_lds[8 * tid + j] = ab[j] - E1;
  unsigned S = 256;
  while (S < len) S <<= 1;                       // sort size, <= SCAP
  for (unsigned e = len + tid; e < S; e += STHR) sb[PAD(e)] = 0;
  __syncthreads();

  // ---- Pull candidates: scan the batch's 16K keys (L2-hot). ----
  const unsigned Dfl = D << 20;
  const uint4* kb4 = (const uint4*)(keybuf + (size_t)b * NPB);
  for (int i = tid; i < NPB / 4; i += STHR) {
    uint4 kv = kb4[i];
#pragma unroll
    for (int e = 0; e < 4; ++e) {
      unsigned k = (&kv.x)[e];
      if (k >= Dfl) {                            // bin >= D (candidate anywhere)
        unsigned bin = k >> 20;
        if (ab_lds[bin] < len) {                 // racy pre-check (monotonic-safe)
          unsigned slot = atomicAdd(&ab_lds[bin], 1u);
          if (slot < len) {
            unsigned li = (unsigned)(4 * i + e); // row within batch
            sb[PAD(slot)] = ((unsigned long long)k << 32) | (unsigned)~li;
          }
        }
      }
    }
  }
  __syncthreads();

  // ---- Wave-cooperative bitonic sort, descending, adaptive size S. ----
  const int nseg = (int)(S >> 7);                // 128-elem segments (2/4/8)
  const int g0 = 128 * wid + lane;               // my reg-0 element index
  const int g1 = g0 + 64;                        // my reg-1 element index
  unsigned long long r0 = 0, r1 = 0;

  // Phase A: full 128-sort per wave, in registers, zero barriers.
  if (wid < nseg) {
    r0 = sb[PAD(g0)]; r1 = sb[PAD(g1)];
    for (unsigned size = 2; size <= 128; size <<= 1) {
      const bool d0 = ((g0 & size) == 0), d1 = ((g1 & size) == 0);
      for (unsigned st = size >> 1; st >= 1; st >>= 1) {
        if (st == 64) {                          // cross-register, same lane
          if ((r0 < r1) == d0) { unsigned long long t_ = r0; r0 = r1; r1 = t_; }
        } else {
          unsigned long long y0 = __shfl_xor(r0, (int)st);
          unsigned long long y1 = __shfl_xor(r1, (int)st);
          const bool lower = ((lane & st) == 0);
          r0 = ((d0 == lower) == (r0 > y0)) ? r0 : y0;
          r1 = ((d1 == lower) == (r1 > y1)) ? r1 : y1;
        }
      }
    }
    sb[PAD(g0)] = r0; sb[PAD(g1)] = r1;
  }
  __syncthreads();

  // Phase B: merges. Cross-segment strides via LDS; final 128 in registers.
  for (unsigned size = 256; size <= S; size <<= 1) {
    for (unsigned st = size >> 1; st >= 128; st >>= 1) {
      const int t = tid;
      if (t < (int)(S / 2)) {
        int pos = 2 * t - (t & ((int)st - 1));
        bool desc = ((pos & size) == 0);
        unsigned long long a = sb[PAD(pos)], bb = sb[PAD(pos + (int)st)];
        if (desc ? (a < bb) : (a > bb)) { sb[PAD(pos)] = bb; sb[PAD(pos + (int)st)] = a; }
      }
      __syncthreads();
    }
    if (wid < nseg) {                            // 128-merge in registers
      r0 = sb[PAD(g0)]; r1 = sb[PAD(g1)];
      const bool d = (((unsigned)(128 * wid) & size) == 0);
      if ((r0 < r1) == d) { unsigned long long t_ = r0; r0 = r1; r1 = t_; }
      for (unsigned st = 32; st >= 1; st >>= 1) {
        unsigned long long y0 = __shfl_xor(r0, (int)st);
        unsigned long long y1 = __shfl_xor(r1, (int)st);
        const bool lower = ((lane & st) == 0);
        r0 = ((d == lower) == (r0 > y0)) ? r0 : y0;
        r1 = ((d == lower) == (r1 > y1)) ? r1 : y1;
      }
      sb[PAD(g0)] = r0; sb[PAD(g1)] = r1;
    }
    __syncthreads();
  }

  // ---- Gather output rows [E1, gend). ----
  const unsigned gend = (E2 < KTOP) ? E2 : KTOP;
  const int glen = (int)(gend - E1);
  const float4* inb = (const float4*)(in + (size_t)b * NPB * NF);
  float4* outb = (float4*)(out + ((size_t)b * KTOP + E1) * NF);
  for (int u = tid; u < glen * 16; u += STHR) {
    int r = u >> 4, f4 = u & 15;
    unsigned long long kv = sb[PAD(r)];
    int gi = (int)(~(unsigned)(kv & 0xffffffffu));
    outb[(size_t)r * 16 + f4] = inb[(size_t)gi * 16 + f4];
  }
}

extern "C" void kernel_launch(void* const* d_in, const int* in_sizes, int n_in,
                              void* d_out, int out_size, void* d_ws, size_t ws_size,
                              hipStream_t stream) {
  const float* in = (const float*)d_in[0];
  float* out = (float*)d_out;

  // d_ws layout: keybuf @0 (2 MiB), subhist u16 @2 MiB (2 MiB).
  unsigned* keybuf    = (unsigned*)d_ws;
  unsigned* subhist32 = (unsigned*)((char*)d_ws + (2u << 20));
  unsigned short* subhist16 = (unsigned short*)subhist32;

  extract_hist_kernel<<<NB * NCH, 1024, 0, stream>>>(in, keybuf, subhist32);
  select_sort_gather_kernel<<<NB * NCH, STHR, 0, stream>>>(in, keybuf, subhist16, out);
}